// Round 4
// baseline (824.103 us; speedup 1.0000x reference)
//
#include <hip/hip_runtime.h>

typedef __attribute__((ext_vector_type(8))) short bf16x8;
typedef __attribute__((ext_vector_type(4))) float f32x4;

#define B_    32
#define CIN   1024
#define H_    37
#define W_    37
#define HP    39          // padded spatial
#define DIM   512
#define COUT  120
#define M1    43808       // B*H*W

// async global->LDS DMA, 16 B per lane, dest = wave-uniform base + lane*16
#define GLOAD_LDS(g, l) __builtin_amdgcn_global_load_lds( \
    (const __attribute__((address_space(1))) void*)(g),   \
    (__attribute__((address_space(3))) void*)(l), 16, 0, 0)

// fp32 -> bf16 round-to-nearest-even
__device__ __forceinline__ unsigned short f2bf(float f) {
    unsigned int u = __float_as_uint(f);
    unsigned int r = 0x7fffu + ((u >> 16) & 1u);
    return (unsigned short)((u + r) >> 16);
}

// ---------------------------------------------------------------------------
// K0a: zero the border ring of nhwc [32][39][39][1024]. 152 border positions
// per image; 32*152*1024/8 = 622,592 int4 -> 2432 blocks exactly.
// ---------------------------------------------------------------------------
__global__ __launch_bounds__(256) void zero_border(unsigned short* __restrict__ nhwc)
{
    const int g = blockIdx.x * 256 + threadIdx.x;
    const int e = g * 8;
    const int per_img = 152 * 1024;
    const int image = e / per_img;
    const int rem = e - image * per_img;
    const int posIdx = rem >> 10;
    const int ci = rem & 1023;
    int y, x;
    if (posIdx < 39)       { y = 0;  x = posIdx; }
    else if (posIdx < 78)  { y = 38; x = posIdx - 39; }
    else if (posIdx < 115) { x = 0;  y = 1 + (posIdx - 78); }
    else                   { x = 38; y = 1 + (posIdx - 115); }
    unsigned short* dst = nhwc + (((size_t)(image * HP + y) * HP + x) << 10) + ci;
    *(int4*)dst = (int4){0, 0, 0, 0};
}

// ---------------------------------------------------------------------------
// K0: NCHW fp32 -> padded NHWC bf16 [32][39][39][1024], interior only.
// One block = (b, y, 256-ci tile). Phase 2 vectorized to int4 stores.
// ---------------------------------------------------------------------------
__global__ __launch_bounds__(256) void pad_transpose(
    const float* __restrict__ fmap, unsigned short* __restrict__ nhwc)
{
    __shared__ float lds[37 * 260];  // stride 260: 16B-aligned rows, bank-spread
    const int t = threadIdx.x;
    const int bid = blockIdx.x;
    const int citile = bid & 3;
    const int rest = bid >> 2;
    const int y = rest % 37;
    const int b = rest / 37;
    const int ci0 = citile * 256;

    const float* src = fmap + ((size_t)(b * CIN + ci0)) * 1369 + y * W_;
    #pragma unroll 1
    for (int k = 0; k < 37; ++k) {
        unsigned int flat = (unsigned)(k * 256 + t);   // = cl*37 + xx
        unsigned int cl = flat / 37u;
        unsigned int xx = flat - cl * 37u;
        lds[xx * 260 + cl] = src[(size_t)cl * 1369 + xx];
    }
    __syncthreads();
    unsigned short* dst = nhwc + ((size_t)(b * HP + y + 1) * HP + 1) * CIN + ci0;
    #pragma unroll 1
    for (int it = 0; it < 5; ++it) {
        int idx = it * 256 + t;                // 1184 int4 stores total
        if (idx < 1184) {
            int xx = idx >> 5;                 // 32 int4 per output row
            int seg = idx & 31;
            const float* p = lds + xx * 260 + seg * 8;
            float4 f0 = *(const float4*)p;
            float4 f1 = *(const float4*)(p + 4);
            union { int4 i4; unsigned short s[8]; } u;
            u.s[0] = f2bf(f0.x); u.s[1] = f2bf(f0.y);
            u.s[2] = f2bf(f0.z); u.s[3] = f2bf(f0.w);
            u.s[4] = f2bf(f1.x); u.s[5] = f2bf(f1.y);
            u.s[6] = f2bf(f1.z); u.s[7] = f2bf(f1.w);
            *(int4*)(dst + (size_t)xx * CIN + seg * 8) = u.i4;
        }
    }
}

// ---------------------------------------------------------------------------
// K1: w1 [512][1024][3][3] fp32 -> [512][9][1024] bf16 via LDS transpose.
// Padded LDS stride (1040) kills the 16-way write conflicts; int4 writes.
// ---------------------------------------------------------------------------
__global__ __launch_bounds__(256) void reorder_w1(
    const float* __restrict__ w1, unsigned short* __restrict__ w1b)
{
    __shared__ unsigned short lds[9 * 1040];
    const int n = blockIdx.x;
    const int t = threadIdx.x;
    const float* src = w1 + (size_t)n * 9216;
    #pragma unroll 1
    for (int i = 0; i < 36; ++i) {
        int flat = i * 256 + t;            // = ci*9 + kk
        int ci = flat / 9;
        int kk = flat - ci * 9;
        lds[kk * 1040 + ci] = f2bf(src[flat]);
    }
    __syncthreads();
    unsigned short* dst = w1b + (size_t)n * 9216;
    #pragma unroll 1
    for (int i = 0; i < 5; ++i) {          // 1152 int4
        int id = i * 256 + t;
        if (id < 1152) {
            int s = id * 8;
            int kk = s >> 10;
            int ci = s & 1023;
            *(int4*)(dst + s) = *(const int4*)(lds + kk * 1040 + ci);
        }
    }
}

// ---------------------------------------------------------------------------
// K2: w2 [120][512] fp32 -> bf16 (layout already [n][k])
// ---------------------------------------------------------------------------
__global__ __launch_bounds__(256) void cast_w2(
    const float* __restrict__ w2, unsigned short* __restrict__ w2b)
{
    int g = blockIdx.x * 256 + threadIdx.x;
    if (g < COUT * DIM) w2b[g] = f2bf(w2[g]);
}

// ---------------------------------------------------------------------------
// K3: implicit GEMM conv3x3: M=43808, N=512, K=9216, BM=BN=128, BK=64
// (unchanged from round 3: global_load_lds staging, XCD swizzle).
// ---------------------------------------------------------------------------
__global__ __launch_bounds__(256, 2) void conv1_gemm(
    const unsigned short* __restrict__ nhwc,
    const unsigned short* __restrict__ w1b,
    const float* __restrict__ b1,
    unsigned short* __restrict__ x1)
{
    __shared__ unsigned short aLds[2 * 128 * 32];   // [kc][row][32]
    __shared__ unsigned short bLds[2 * 128 * 32];

    const int bid = blockIdx.x;                    // 1376 blocks
    const int xcd = bid & 7;
    const int u = bid >> 3;
    const int mtile = xcd * 43 + (u >> 2);
    const int ntile = u & 3;
    if (mtile >= 343) return;                      // uniform exit, pre-barrier
    const int m0 = mtile * 128;
    const int n0 = ntile * 128;

    const int t = threadIdx.x;
    const int w = t >> 6;
    const int l = t & 63;
    const int rowc = l >> 2;
    const int seg = l & 3;
    const int rowA0 = w * 32 + rowc;
    const int rowA1 = rowA0 + 16;

    int mA0 = m0 + rowA0; if (mA0 >= M1) mA0 = M1 - 1;
    int mA1 = m0 + rowA1; if (mA1 >= M1) mA1 = M1 - 1;
    int bi0 = mA0 / 1369, rr0 = mA0 % 1369;
    int bi1 = mA1 / 1369, rr1 = mA1 % 1369;
    const int pos0 = (bi0 * HP + rr0 / 37) * HP + rr0 % 37;
    const int pos1 = (bi1 * HP + rr1 / 37) * HP + rr1 % 37;

    const unsigned short* bRow0 = w1b + (size_t)(n0 + rowA0) * 9216 + seg * 8;
    const unsigned short* bRow1 = w1b + (size_t)(n0 + rowA1) * 9216 + seg * 8;

    const int wm = w & 1, wn = w >> 1;
    const int lr = l & 15, quad = l >> 4;

    f32x4 acc[4][4];
    #pragma unroll
    for (int i = 0; i < 4; ++i)
        #pragma unroll
        for (int j = 0; j < 4; ++j)
            acc[i][j] = (f32x4){0.f, 0.f, 0.f, 0.f};

    for (int kykx = 0; kykx < 9; ++kykx) {
        const int ky = kykx / 3, kx = kykx - ky * 3;
        const unsigned short* aG0 = nhwc + (((size_t)(pos0 + ky * HP + kx)) << 10) + seg * 8;
        const unsigned short* aG1 = nhwc + (((size_t)(pos1 + ky * HP + kx)) << 10) + seg * 8;
        const unsigned short* bG0 = bRow0 + kykx * 1024;
        const unsigned short* bG1 = bRow1 + kykx * 1024;
        #pragma unroll 1
        for (int ci0 = 0; ci0 < 1024; ci0 += 64) {
            __syncthreads();
            GLOAD_LDS(aG0 + ci0,      aLds + w * 1024);
            GLOAD_LDS(aG1 + ci0,      aLds + w * 1024 + 512);
            GLOAD_LDS(aG0 + ci0 + 32, aLds + 4096 + w * 1024);
            GLOAD_LDS(aG1 + ci0 + 32, aLds + 4096 + w * 1024 + 512);
            GLOAD_LDS(bG0 + ci0,      bLds + w * 1024);
            GLOAD_LDS(bG1 + ci0,      bLds + w * 1024 + 512);
            GLOAD_LDS(bG0 + ci0 + 32, bLds + 4096 + w * 1024);
            GLOAD_LDS(bG1 + ci0 + 32, bLds + 4096 + w * 1024 + 512);
            __syncthreads();
            #pragma unroll
            for (int kc = 0; kc < 2; ++kc) {
                bf16x8 af[4], bfr[4];
                #pragma unroll
                for (int i = 0; i < 4; ++i)
                    af[i] = *(const bf16x8*)(aLds + kc * 4096 +
                                             (wm * 64 + i * 16 + lr) * 32 + quad * 8);
                #pragma unroll
                for (int j = 0; j < 4; ++j)
                    bfr[j] = *(const bf16x8*)(bLds + kc * 4096 +
                                              (wn * 64 + j * 16 + lr) * 32 + quad * 8);
                #pragma unroll
                for (int i = 0; i < 4; ++i)
                    #pragma unroll
                    for (int j = 0; j < 4; ++j)
                        acc[i][j] = __builtin_amdgcn_mfma_f32_16x16x32_bf16(
                            af[i], bfr[j], acc[i][j], 0, 0, 0);
            }
        }
    }

    #pragma unroll
    for (int i = 0; i < 4; ++i) {
        const int mloc = m0 + wm * 64 + i * 16 + quad * 4;
        #pragma unroll
        for (int j = 0; j < 4; ++j) {
            const int n = n0 + wn * 64 + j * 16 + lr;
            const float bias = b1[n];
            #pragma unroll
            for (int r = 0; r < 4; ++r) {
                const int m = mloc + r;
                if (m < M1) {
                    float v = acc[i][j][r] + bias;
                    v = fminf(fmaxf(v, 0.f), 6.f);
                    x1[(size_t)m * DIM + n] = f2bf(v);
                }
            }
        }
    }
}

// ---------------------------------------------------------------------------
// K4 v2: conv1x1 GEMM, barrier-light. BM=64/block (685 blocks, ~2.7/CU).
// w2 staged in LDS in four 128-K phases (padded stride 136 -> conflict-free);
// all 16 A-fragments prefetched to registers; A never touches LDS.
// ---------------------------------------------------------------------------
#define BST 136   // LDS row stride in shorts (272 B = 68 dw, spreads banks)
__global__ __launch_bounds__(256, 2) void conv2_gemm(
    const unsigned short* __restrict__ x1,
    const unsigned short* __restrict__ w2b,
    const float* __restrict__ b2,
    float* __restrict__ out)
{
    __shared__ unsigned short bsh[128 * BST];   // 34,816 B

    const int t = threadIdx.x;
    const int wv = t >> 6;
    const int l = t & 63;
    const int lr = l & 15, quad = l >> 4;
    const int m0 = blockIdx.x * 64;

    // prefetch all 16 A fragments (K=512) for this lane's row
    int am = m0 + wv * 16 + lr; if (am >= M1) am = M1 - 1;
    const unsigned short* aRow = x1 + (size_t)am * DIM + quad * 8;
    bf16x8 afv[16];
    #pragma unroll
    for (int q = 0; q < 16; ++q)
        afv[q] = *(const bf16x8*)(aRow + q * 32);

    f32x4 acc[8];
    #pragma unroll
    for (int j = 0; j < 8; ++j) acc[j] = (f32x4){0.f, 0.f, 0.f, 0.f};

    #pragma unroll 1
    for (int ph = 0; ph < 4; ++ph) {
        __syncthreads();                        // protect prev-phase LDS reads
        #pragma unroll
        for (int it = 0; it < 8; ++it) {        // stage B phase: 2048 int4
            int id = it * 256 + t;
            int row = id >> 4;                  // 0..127
            int ks = id & 15;
            int4 v = (int4){0, 0, 0, 0};
            if (row < COUT)
                v = *(const int4*)(w2b + (size_t)row * DIM + ph * 128 + ks * 8);
            *(int4*)(bsh + row * BST + ks * 8) = v;
        }
        __syncthreads();
        #pragma unroll
        for (int kk = 0; kk < 4; ++kk) {
            bf16x8 af = afv[ph * 4 + kk];
            #pragma unroll
            for (int j = 0; j < 8; ++j) {
                bf16x8 bf = *(const bf16x8*)(bsh + (j * 16 + lr) * BST + kk * 32 + quad * 8);
                acc[j] = __builtin_amdgcn_mfma_f32_16x16x32_bf16(af, bf, acc[j], 0, 0, 0);
            }
        }
    }

    #pragma unroll
    for (int j = 0; j < 8; ++j) {
        const int n = j * 16 + lr;
        if (n >= COUT) continue;
        const float bias = b2[n];
        #pragma unroll
        for (int r = 0; r < 4; ++r) {
            const int m = m0 + wv * 16 + quad * 4 + r;
            if (m < M1)
                out[(size_t)m * COUT + n] = acc[j][r] + bias;
        }
    }
}

// ---------------------------------------------------------------------------
extern "C" void kernel_launch(void* const* d_in, const int* in_sizes, int n_in,
                              void* d_out, int out_size, void* d_ws, size_t ws_size,
                              hipStream_t stream)
{
    const float* fmap = (const float*)d_in[0];
    const float* w1   = (const float*)d_in[1];
    const float* b1   = (const float*)d_in[2];
    const float* w2   = (const float*)d_in[3];
    const float* b2   = (const float*)d_in[4];
    float* out = (float*)d_out;

    char* ws = (char*)d_ws;
    const size_t NHWC_BYTES = (size_t)B_ * HP * HP * CIN * 2;        // 99,680,256
    const size_t W1B_BYTES  = (size_t)DIM * 9 * CIN * 2;             //  9,437,184
    const size_t W2B_BYTES  = (size_t)COUT * DIM * 2;                //    122,880
    unsigned short* nhwc = (unsigned short*)ws;
    unsigned short* w1b  = (unsigned short*)(ws + NHWC_BYTES);
    unsigned short* w2b  = (unsigned short*)(ws + NHWC_BYTES + W1B_BYTES);
    unsigned short* x1   = (unsigned short*)(ws + NHWC_BYTES + W1B_BYTES + W2B_BYTES);

    zero_border<<<2432, 256, 0, stream>>>(nhwc);
    pad_transpose<<<B_ * 37 * 4, 256, 0, stream>>>(fmap, nhwc);
    reorder_w1<<<DIM, 256, 0, stream>>>(w1, w1b);
    cast_w2<<<(COUT * DIM + 255) / 256, 256, 0, stream>>>(w2, w2b);

    conv1_gemm<<<344 * 4, 256, 0, stream>>>(nhwc, w1b, b1, x1);
    conv2_gemm<<<(M1 + 63) / 64, 256, 0, stream>>>(x1, w2b, b2, out);
}

// Round 5
// 789.593 us; speedup vs baseline: 1.0437x; 1.0437x over previous
//
#include <hip/hip_runtime.h>

typedef __attribute__((ext_vector_type(8))) short bf16x8;
typedef __attribute__((ext_vector_type(4))) float f32x4;

#define B_    32
#define CIN   1024
#define H_    37
#define W_    37
#define HP    39          // padded spatial
#define DIM   512
#define COUT  120
#define M1    43808       // B*H*W

// async global->LDS DMA, 16 B per lane, dest = wave-uniform base + lane*16
#define GLOAD_LDS(g, l) __builtin_amdgcn_global_load_lds( \
    (const __attribute__((address_space(1))) void*)(g),   \
    (__attribute__((address_space(3))) void*)(l), 16, 0, 0)

// fp32 -> bf16 round-to-nearest-even
__device__ __forceinline__ unsigned short f2bf(float f) {
    unsigned int u = __float_as_uint(f);
    unsigned int r = 0x7fffu + ((u >> 16) & 1u);
    return (unsigned short)((u + r) >> 16);
}

// ---------------------------------------------------------------------------
// PREP (fused): all input transforms in ONE dispatch, branch by block range.
//   [0, 4736)        : pad_transpose  — NCHW fp32 -> padded NHWC bf16 interior
//   [4736, 7168)     : zero_border    — border ring of nhwc
//   [7168, 7680)     : reorder_w1     — w1 [512][1024][3][3] -> [512][9][1024]
//   [7680, 7710)     : cast_w2        — w2 fp32 -> bf16
// All branches write disjoint buffers; conv1 launch is the consumer barrier.
// ---------------------------------------------------------------------------
#define PAD_BLKS   4736
#define ZERO_BLKS  2432
#define RW1_BLKS   512
#define CW2_BLKS   30
#define PREP_BLKS  (PAD_BLKS + ZERO_BLKS + RW1_BLKS + CW2_BLKS)

__global__ __launch_bounds__(256) void prep(
    const float* __restrict__ fmap, const float* __restrict__ w1,
    const float* __restrict__ w2,
    unsigned short* __restrict__ nhwc, unsigned short* __restrict__ w1b,
    unsigned short* __restrict__ w2b)
{
    __shared__ __attribute__((aligned(16))) char smem_raw[37 * 260 * 4];
    const int bid = blockIdx.x;
    const int t = threadIdx.x;

    if (bid < PAD_BLKS) {
        // ---- pad_transpose: one block = (b, y, 256-ci tile) ----
        float* lds = (float*)smem_raw;          // [37][260]
        const int citile = bid & 3;
        const int rest = bid >> 2;
        const int y = rest % 37;
        const int b = rest / 37;
        const int ci0 = citile * 256;

        const float* src = fmap + ((size_t)(b * CIN + ci0)) * 1369 + y * W_;
        #pragma unroll 1
        for (int k = 0; k < 37; ++k) {
            unsigned int flat = (unsigned)(k * 256 + t);   // = cl*37 + xx
            unsigned int cl = flat / 37u;
            unsigned int xx = flat - cl * 37u;
            lds[xx * 260 + cl] = src[(size_t)cl * 1369 + xx];
        }
        __syncthreads();
        unsigned short* dst = nhwc + ((size_t)(b * HP + y + 1) * HP + 1) * CIN + ci0;
        #pragma unroll 1
        for (int it = 0; it < 5; ++it) {
            int idx = it * 256 + t;                // 1184 int4 stores total
            if (idx < 1184) {
                int xx = idx >> 5;                 // 32 int4 per output row
                int seg = idx & 31;
                const float* p = lds + xx * 260 + seg * 8;
                float4 f0 = *(const float4*)p;
                float4 f1 = *(const float4*)(p + 4);
                union { int4 i4; unsigned short s[8]; } u;
                u.s[0] = f2bf(f0.x); u.s[1] = f2bf(f0.y);
                u.s[2] = f2bf(f0.z); u.s[3] = f2bf(f0.w);
                u.s[4] = f2bf(f1.x); u.s[5] = f2bf(f1.y);
                u.s[6] = f2bf(f1.z); u.s[7] = f2bf(f1.w);
                *(int4*)(dst + (size_t)xx * CIN + seg * 8) = u.i4;
            }
        }
    } else if (bid < PAD_BLKS + ZERO_BLKS) {
        // ---- zero_border: 152 border positions/img, 8 shorts per thread ----
        const int g = (bid - PAD_BLKS) * 256 + t;
        const int e = g * 8;
        const int per_img = 152 * 1024;
        const int image = e / per_img;
        const int rem = e - image * per_img;
        const int posIdx = rem >> 10;
        const int ci = rem & 1023;
        int y, x;
        if (posIdx < 39)       { y = 0;  x = posIdx; }
        else if (posIdx < 78)  { y = 38; x = posIdx - 39; }
        else if (posIdx < 115) { x = 0;  y = 1 + (posIdx - 78); }
        else                   { x = 38; y = 1 + (posIdx - 115); }
        unsigned short* dst = nhwc + (((size_t)(image * HP + y) * HP + x) << 10) + ci;
        *(int4*)dst = (int4){0, 0, 0, 0};
    } else if (bid < PAD_BLKS + ZERO_BLKS + RW1_BLKS) {
        // ---- reorder_w1: one block per n, LDS transpose ----
        unsigned short* lds = (unsigned short*)smem_raw;  // [9][1040]
        const int n = bid - (PAD_BLKS + ZERO_BLKS);
        const float* src = w1 + (size_t)n * 9216;
        #pragma unroll 1
        for (int i = 0; i < 36; ++i) {
            int flat = i * 256 + t;            // = ci*9 + kk
            int ci = flat / 9;
            int kk = flat - ci * 9;
            lds[kk * 1040 + ci] = f2bf(src[flat]);
        }
        __syncthreads();
        unsigned short* dst = w1b + (size_t)n * 9216;
        #pragma unroll 1
        for (int i = 0; i < 5; ++i) {          // 1152 int4
            int id = i * 256 + t;
            if (id < 1152) {
                int s = id * 8;
                int kk = s >> 10;
                int ci = s & 1023;
                *(int4*)(dst + s) = *(const int4*)(lds + kk * 1040 + ci);
            }
        }
    } else {
        // ---- cast_w2: 8 elems/thread, vectorized ----
        const int g = (bid - (PAD_BLKS + ZERO_BLKS + RW1_BLKS)) * 256 + t;
        if (g < COUT * DIM / 8) {
            const int s = g * 8;
            float4 f0 = *(const float4*)(w2 + s);
            float4 f1 = *(const float4*)(w2 + s + 4);
            union { int4 i4; unsigned short sh[8]; } u;
            u.sh[0] = f2bf(f0.x); u.sh[1] = f2bf(f0.y);
            u.sh[2] = f2bf(f0.z); u.sh[3] = f2bf(f0.w);
            u.sh[4] = f2bf(f1.x); u.sh[5] = f2bf(f1.y);
            u.sh[6] = f2bf(f1.z); u.sh[7] = f2bf(f1.w);
            *(int4*)(w2b + s) = u.i4;
        }
    }
}

// ---------------------------------------------------------------------------
// K3: implicit GEMM conv3x3: M=43808, N=512, K=9216, BM=BN=128, BK=64.
// global_load_lds staging + XCD swizzle. launch_bounds min-waves hint
// REMOVED: LDS 32 KB allows 5 blocks/CU — let occupancy rise so co-resident
// blocks overlap each other's barrier drains.
// ---------------------------------------------------------------------------
__global__ __launch_bounds__(256) void conv1_gemm(
    const unsigned short* __restrict__ nhwc,
    const unsigned short* __restrict__ w1b,
    const float* __restrict__ b1,
    unsigned short* __restrict__ x1)
{
    __shared__ unsigned short aLds[2 * 128 * 32];   // [kc][row][32]
    __shared__ unsigned short bLds[2 * 128 * 32];

    const int bid = blockIdx.x;                    // 1376 blocks
    const int xcd = bid & 7;
    const int u = bid >> 3;
    const int mtile = xcd * 43 + (u >> 2);
    const int ntile = u & 3;
    if (mtile >= 343) return;                      // uniform exit, pre-barrier
    const int m0 = mtile * 128;
    const int n0 = ntile * 128;

    const int t = threadIdx.x;
    const int w = t >> 6;
    const int l = t & 63;
    const int rowc = l >> 2;
    const int seg = l & 3;
    const int rowA0 = w * 32 + rowc;
    const int rowA1 = rowA0 + 16;

    int mA0 = m0 + rowA0; if (mA0 >= M1) mA0 = M1 - 1;
    int mA1 = m0 + rowA1; if (mA1 >= M1) mA1 = M1 - 1;
    int bi0 = mA0 / 1369, rr0 = mA0 % 1369;
    int bi1 = mA1 / 1369, rr1 = mA1 % 1369;
    const int pos0 = (bi0 * HP + rr0 / 37) * HP + rr0 % 37;
    const int pos1 = (bi1 * HP + rr1 / 37) * HP + rr1 % 37;

    const unsigned short* bRow0 = w1b + (size_t)(n0 + rowA0) * 9216 + seg * 8;
    const unsigned short* bRow1 = w1b + (size_t)(n0 + rowA1) * 9216 + seg * 8;

    const int wm = w & 1, wn = w >> 1;
    const int lr = l & 15, quad = l >> 4;

    f32x4 acc[4][4];
    #pragma unroll
    for (int i = 0; i < 4; ++i)
        #pragma unroll
        for (int j = 0; j < 4; ++j)
            acc[i][j] = (f32x4){0.f, 0.f, 0.f, 0.f};

    for (int kykx = 0; kykx < 9; ++kykx) {
        const int ky = kykx / 3, kx = kykx - ky * 3;
        const unsigned short* aG0 = nhwc + (((size_t)(pos0 + ky * HP + kx)) << 10) + seg * 8;
        const unsigned short* aG1 = nhwc + (((size_t)(pos1 + ky * HP + kx)) << 10) + seg * 8;
        const unsigned short* bG0 = bRow0 + kykx * 1024;
        const unsigned short* bG1 = bRow1 + kykx * 1024;
        #pragma unroll 1
        for (int ci0 = 0; ci0 < 1024; ci0 += 64) {
            __syncthreads();
            GLOAD_LDS(aG0 + ci0,      aLds + w * 1024);
            GLOAD_LDS(aG1 + ci0,      aLds + w * 1024 + 512);
            GLOAD_LDS(aG0 + ci0 + 32, aLds + 4096 + w * 1024);
            GLOAD_LDS(aG1 + ci0 + 32, aLds + 4096 + w * 1024 + 512);
            GLOAD_LDS(bG0 + ci0,      bLds + w * 1024);
            GLOAD_LDS(bG1 + ci0,      bLds + w * 1024 + 512);
            GLOAD_LDS(bG0 + ci0 + 32, bLds + 4096 + w * 1024);
            GLOAD_LDS(bG1 + ci0 + 32, bLds + 4096 + w * 1024 + 512);
            __syncthreads();
            #pragma unroll
            for (int kc = 0; kc < 2; ++kc) {
                bf16x8 af[4], bfr[4];
                #pragma unroll
                for (int i = 0; i < 4; ++i)
                    af[i] = *(const bf16x8*)(aLds + kc * 4096 +
                                             (wm * 64 + i * 16 + lr) * 32 + quad * 8);
                #pragma unroll
                for (int j = 0; j < 4; ++j)
                    bfr[j] = *(const bf16x8*)(bLds + kc * 4096 +
                                              (wn * 64 + j * 16 + lr) * 32 + quad * 8);
                #pragma unroll
                for (int i = 0; i < 4; ++i)
                    #pragma unroll
                    for (int j = 0; j < 4; ++j)
                        acc[i][j] = __builtin_amdgcn_mfma_f32_16x16x32_bf16(
                            af[i], bfr[j], acc[i][j], 0, 0, 0);
            }
        }
    }

    #pragma unroll
    for (int i = 0; i < 4; ++i) {
        const int mloc = m0 + wm * 64 + i * 16 + quad * 4;
        #pragma unroll
        for (int j = 0; j < 4; ++j) {
            const int n = n0 + wn * 64 + j * 16 + lr;
            const float bias = b1[n];
            #pragma unroll
            for (int r = 0; r < 4; ++r) {
                const int m = mloc + r;
                if (m < M1) {
                    float v = acc[i][j][r] + bias;
                    v = fminf(fmaxf(v, 0.f), 6.f);
                    x1[(size_t)m * DIM + n] = f2bf(v);
                }
            }
        }
    }
}

// ---------------------------------------------------------------------------
// K4: conv1x1 GEMM, barrier-light. BM=64/block (685 blocks).
// w2 staged in LDS in four 128-K phases; A prefetched to registers.
// ---------------------------------------------------------------------------
#define BST 136   // LDS row stride in shorts
__global__ __launch_bounds__(256, 2) void conv2_gemm(
    const unsigned short* __restrict__ x1,
    const unsigned short* __restrict__ w2b,
    const float* __restrict__ b2,
    float* __restrict__ out)
{
    __shared__ unsigned short bsh[128 * BST];   // 34,816 B

    const int t = threadIdx.x;
    const int wv = t >> 6;
    const int l = t & 63;
    const int lr = l & 15, quad = l >> 4;
    const int m0 = blockIdx.x * 64;

    int am = m0 + wv * 16 + lr; if (am >= M1) am = M1 - 1;
    const unsigned short* aRow = x1 + (size_t)am * DIM + quad * 8;
    bf16x8 afv[16];
    #pragma unroll
    for (int q = 0; q < 16; ++q)
        afv[q] = *(const bf16x8*)(aRow + q * 32);

    f32x4 acc[8];
    #pragma unroll
    for (int j = 0; j < 8; ++j) acc[j] = (f32x4){0.f, 0.f, 0.f, 0.f};

    #pragma unroll 1
    for (int ph = 0; ph < 4; ++ph) {
        __syncthreads();
        #pragma unroll
        for (int it = 0; it < 8; ++it) {
            int id = it * 256 + t;
            int row = id >> 4;
            int ks = id & 15;
            int4 v = (int4){0, 0, 0, 0};
            if (row < COUT)
                v = *(const int4*)(w2b + (size_t)row * DIM + ph * 128 + ks * 8);
            *(int4*)(bsh + row * BST + ks * 8) = v;
        }
        __syncthreads();
        #pragma unroll
        for (int kk = 0; kk < 4; ++kk) {
            bf16x8 af = afv[ph * 4 + kk];
            #pragma unroll
            for (int j = 0; j < 8; ++j) {
                bf16x8 bf = *(const bf16x8*)(bsh + (j * 16 + lr) * BST + kk * 32 + quad * 8);
                acc[j] = __builtin_amdgcn_mfma_f32_16x16x32_bf16(af, bf, acc[j], 0, 0, 0);
            }
        }
    }

    #pragma unroll
    for (int j = 0; j < 8; ++j) {
        const int n = j * 16 + lr;
        if (n >= COUT) continue;
        const float bias = b2[n];
        #pragma unroll
        for (int r = 0; r < 4; ++r) {
            const int m = m0 + wv * 16 + quad * 4 + r;
            if (m < M1)
                out[(size_t)m * COUT + n] = acc[j][r] + bias;
        }
    }
}

// ---------------------------------------------------------------------------
extern "C" void kernel_launch(void* const* d_in, const int* in_sizes, int n_in,
                              void* d_out, int out_size, void* d_ws, size_t ws_size,
                              hipStream_t stream)
{
    const float* fmap = (const float*)d_in[0];
    const float* w1   = (const float*)d_in[1];
    const float* b1   = (const float*)d_in[2];
    const float* w2   = (const float*)d_in[3];
    const float* b2   = (const float*)d_in[4];
    float* out = (float*)d_out;

    char* ws = (char*)d_ws;
    const size_t NHWC_BYTES = (size_t)B_ * HP * HP * CIN * 2;        // 99,680,256
    const size_t W1B_BYTES  = (size_t)DIM * 9 * CIN * 2;             //  9,437,184
    const size_t W2B_BYTES  = (size_t)COUT * DIM * 2;                //    122,880
    unsigned short* nhwc = (unsigned short*)ws;
    unsigned short* w1b  = (unsigned short*)(ws + NHWC_BYTES);
    unsigned short* w2b  = (unsigned short*)(ws + NHWC_BYTES + W1B_BYTES);
    unsigned short* x1   = (unsigned short*)(ws + NHWC_BYTES + W1B_BYTES + W2B_BYTES);

    prep<<<PREP_BLKS, 256, 0, stream>>>(fmap, w1, w2, nhwc, w1b, w2b);
    conv1_gemm<<<344 * 4, 256, 0, stream>>>(nhwc, w1b, b1, x1);
    conv2_gemm<<<(M1 + 63) / 64, 256, 0, stream>>>(x1, w2b, b2, out);
}